// Round 4
// baseline (3004.443 us; speedup 1.0000x reference)
//
#include <hip/hip_runtime.h>
#include <math.h>

// ConvLSTM encoder, MI355X. R13: occupancy 8 -> 12 waves/CU via one
// 768-thread block (3 waves/SIMD, __launch_bounds__(768,3), reg cap 170).
// Rationale: R0->R3 scaling was occupancy-proportional (4 waves 3127us,
// 8 waves 2450us) with 55% issue-idle at 2/SIMD; MFMA floor is 3.5x away.
// Work per wave shrinks 2/3 -> per-lane state fits the tighter cap:
// L0 = 2 tiles/wave (6 m-groups x 2 ch-halves), L1 = one pass of 4 tiles
// (3 m-groups x 4 ch-quarters), single-A + dbuf-B in L1 (~169 regs peak).
// FC tail: shfl-xor wave reduction (no 43KB sacc, fewer live regs).
// + s_setprio(1) around MFMA bursts (T5), + non-temporal wfc2 FC loads
// (stop thrashing wp1 out of L2 -> B-load latency).

typedef __bf16 bf16x8 __attribute__((ext_vector_type(8)));
typedef __bf16 bf16x4 __attribute__((ext_vector_type(4)));
typedef float  f32x4  __attribute__((ext_vector_type(4)));

__device__ __forceinline__ float sigm(float x)  { return 1.f / (1.f + __expf(-x)); }
__device__ __forceinline__ float ftanh(float x) { float e = __expf(2.f * x); return 1.f - 2.f / (e + 1.f); }
__device__ __forceinline__ bf16x8 ntld8(const __bf16* p) {
  return __builtin_nontemporal_load((const bf16x8*)p);
}

// ---------------- workspace layout (bytes) ----------------
#define OFF_WP0  ((size_t)0)          // [2][10][4][64][8] bf16 = 81,920
#define OFF_WP1  ((size_t)81920)      // [4][27][4][64][8] bf16 = 442,368
#define OFF_WFC  ((size_t)524288)     // [168][64][64] bf16 = 1,376,256
#define OFF_WCP0 ((size_t)1900544)    // [3][32][168] bf16 = 32,256
#define OFF_WCP1 ((size_t)1932800)    // [3][64][168] bf16 = 64,512
#define WS_NEED  ((size_t)1997312)

#define SH0N 9360    // 9*26*40 bf16 per h0 buffer (ping-pong)
#define SH1N 16848   // 9*26*72 bf16 per h1 buffer (ping-pong)
#define SX2N 5376    // 168*32 bf16 im2col x (k<18 taps + k=18 bias lane)

// ---------------- weight pack kernels (fragment-ordered) ----------------
// wp0f[((chh*10+s)*4+g)*512 + L*8 + e] = W0(n = g*32+chh*16+(L&15),
//   k = s*32+(L>>4)*8+e), K-order: k<32 im2col-x (k<18 real, k==18 bias),
//   k>=32 h-taps.
__global__ void pack_w0(const float* __restrict__ wx0, const float* __restrict__ wh0,
                        const float* __restrict__ bx0, __bf16* __restrict__ dst) {
  int o = blockIdx.x * 256 + threadIdx.x;
  if (o >= 40960) return;
  int e = o & 7, L = (o >> 3) & 63;
  int idx = o >> 9;
  int g = idx & 3, sidx = idx >> 2;
  int s = sidx % 10, chh = sidx / 10;
  int n = g * 32 + chh * 16 + (L & 15);
  int k = s * 32 + (L >> 4) * 8 + e;
  float v = 0.f;
  if (k < 32) {
    if (k < 18) {
      int ky = k / 6, rem = k - ky * 6, kx = rem >> 1, ci = rem & 1;
      v = wx0[(n * 2 + ci) * 9 + ky * 3 + kx];
    } else if (k == 18) {
      v = bx0[n];                      // bias tap: pairs with sx2[pix][18]=1.0
    }
  } else {
    int tk = k - 32, tap = tk >> 5, c = tk & 31;
    v = wh0[(n * 32 + c) * 9 + tap];
  }
  dst[o] = (__bf16)v;
}

// wp1f[((chq*27+s)*4+g)*512 + L*8 + e] = W1(n = g*64+chq*16+(L&15),
//   k = s*32+(L>>4)*8+e), K-order: k<288 x-conv taps, k>=288 h-taps.
__global__ void pack_w1(const float* __restrict__ wx1, const float* __restrict__ wh1,
                        __bf16* __restrict__ dst) {
  int o = blockIdx.x * 256 + threadIdx.x;
  if (o >= 221184) return;
  int e = o & 7, L = (o >> 3) & 63;
  int idx = o >> 9;
  int g = idx & 3, sidx = idx >> 2;
  int s = sidx % 27, chq = sidx / 27;
  int n = g * 64 + chq * 16 + (L & 15);
  int k = s * 32 + (L >> 4) * 8 + e;
  float v;
  if (k < 288) {
    int tap = k >> 5, c = k & 31;
    v = wx1[(n * 32 + c) * 9 + tap];
  } else {
    int tk = k - 288, s2 = tk >> 5, c = tk & 31, tap = s2 >> 1, hf = s2 & 1;
    v = wh1[(n * 64 + hf * 32 + c) * 9 + tap];
  }
  dst[o] = (__bf16)v;
}

// Wfc2[pix][ch][n] bf16 = fc1_w[n][ch*168+pix]
__global__ void pack_wfc(const float* __restrict__ w, __bf16* __restrict__ dst) {
  int o = blockIdx.x * 256 + threadIdx.x;
  if (o >= 168 * 64 * 64) return;
  int pix = o >> 12, ch = (o >> 6) & 63, n = o & 63;
  dst[o] = (__bf16)w[n * 10752 + ch * 168 + pix];
}

// peephole weights -> bf16 (halves epilogue regs + fetch)
__global__ void pack_wc(const float* __restrict__ wc0, const float* __restrict__ wc1,
                        __bf16* __restrict__ d0, __bf16* __restrict__ d1) {
  int o = blockIdx.x * 256 + threadIdx.x;
  if (o < 16128) d0[o] = (__bf16)wc0[o];
  else if (o < 48384) d1[o - 16128] = (__bf16)wc1[o - 16128];
}

// ---------------- the persistent ConvLSTM kernel ----------------
__global__ __launch_bounds__(768, 3) void convlstm_persistent(
    const float* __restrict__ input, const float* __restrict__ x_ex,
    const __bf16* __restrict__ wp0, const __bf16* __restrict__ wp1,
    const __bf16* __restrict__ wfc2,
    const float* __restrict__ bx1,
    const __bf16* __restrict__ wcp0, const __bf16* __restrict__ wcp1,
    const float* __restrict__ fc1b,
    const float* __restrict__ exw, const float* __restrict__ exb,
    float* __restrict__ out)
{
  // LDS: 37,440 + 67,392 + 10,752 = 115,584 B -> 1 block/CU, 12 waves.
  __shared__ __bf16 sh0[2 * SH0N];   // h0 ping-pong, [y][x][40] halo
  __shared__ __bf16 sh1[2 * SH1N];   // h1 ping-pong, [y][x][72] halo
  __shared__ __bf16 sx2[SX2N];       // im2col x [pix][32], k<=18 used

  const int b = blockIdx.x;
  const int t = threadIdx.x;
  const int w = t >> 6, L = t & 63;
  const int lo16 = L & 15, hi4 = L >> 4;

  // ---- zero LDS ----
  {
    int* p0 = (int*)sh0;
    for (int i = t; i < SH0N; i += 768) p0[i] = 0;       // both h0 buffers
    int* p1 = (int*)sh1;
    for (int i = t; i < SH1N; i += 768) p1[i] = 0;       // both h1 buffers
    int* p2 = (int*)sx2;
    for (int i = t; i < SX2N / 2; i += 768) p2[i] = 0;
  }
  __syncthreads();

  // ---- build im2col x2 (time-constant), [pix][32], k = ky*6+kx*2+cin ----
  if (t < 168) {
    int iy = t / 24, ix = t - iy * 24;
    __bf16* dst = sx2 + t * 32;
    for (int ky = 0; ky < 3; ++ky) {
      int y = iy + ky - 1;
      if (y < 0 || y >= 7) continue;
      for (int kx = 0; kx < 3; ++kx) {
        int x = ix + kx - 1;
        if (x < 0 || x >= 24) continue;
        int k0 = ky * 6 + kx * 2;
        dst[k0 + 0] = (__bf16)input[((b * 2 + 0) * 7 + y) * 24 + x];
        dst[k0 + 1] = (__bf16)input[((b * 2 + 1) * 7 + y) * 24 + x];
      }
    }
    dst[18] = (__bf16)1.0f;          // bias lane (pairs with wp0 k==18 = bx0)
  }

  // ---- wave roles (12 waves) ----
  // L0: (m6 in 0..5: 2 M-tiles each) x (chh in 0..1 ch-half of 32)
  // L1: (m3 in 0..2: 4 M-tiles each) x (chq in 0..3 ch-quarter of 64)
  const int chh = w & 1, m6 = w >> 1;
  const int chq = w & 3, m3 = w >> 2;
  const int ch0 = chh * 16 + lo16;     // layer-0 channel (0..31)
  const int ch1 = chq * 16 + lo16;     // layer-1 channel (0..63)

  const __bf16* w0f = wp0 + chh * 20480 + L * 8;   // + (s*4+g)*512
  const __bf16* w1f = wp1 + chq * 55296 + L * 8;   // + (s*4+g)*512

  const float bi1 = bx1[ch1], bf1 = bx1[64 + ch1];
  const float bg1 = bx1[128 + ch1], bo1 = bx1[192 + ch1];

  float c0r[2][4];                     // layer-0 cell state (8 f32/lane)
#pragma unroll
  for (int j = 0; j < 2; ++j)
#pragma unroll
    for (int r = 0; r < 4; ++r) c0r[j][r] = 0.f;

  float c1r[4][4];                     // layer-1 cell state (16 f32/lane)
#pragma unroll
  for (int j = 0; j < 4; ++j)
#pragma unroll
    for (int r = 0; r < 4; ++r) c1r[j][r] = 0.f;

  __syncthreads();   // x2 + zeroed state visible

#pragma unroll 1
  for (int st = 0; st < 7; ++st) {
    const __bf16* h0r = sh0 + (st & 1) * SH0N;
    __bf16*       h0w = sh0 + ((st + 1) & 1) * SH0N;
    const __bf16* h1r = sh1 + (st & 1) * SH1N;
    __bf16*       h1w = sh1 + ((st + 1) & 1) * SH1N;

    // ============ layer 0: 2 tiles/wave, unroll-2 dbuf ping-pong ==========
    {
      const int tb = m6 * 2;                       // tiles tb, tb+1 (11 dummy)
      const int ntq = (m6 == 5) ? 1 : 2;
      int b0h[2], b0x[2];
#pragma unroll
      for (int j = 0; j < 2; ++j) {
        int pr = (tb + j) * 16 + lo16;
        if (pr > 167) pr = 167;
        int iy = pr / 24, ix = pr - iy * 24;
        b0h[j] = (iy * 26 + ix) * 40;
        b0x[j] = pr * 32 + hi4 * 8;
      }
      f32x4 a0[4][2];
#pragma unroll
      for (int g = 0; g < 4; ++g)
#pragma unroll
        for (int j = 0; j < 2; ++j) a0[g][j] = (f32x4){0.f, 0.f, 0.f, 0.f};

      auto loadA0 = [&](int s, bf16x8* af) {
        if (s == 0) {
#pragma unroll
          for (int j = 0; j < 2; ++j) af[j] = *(const bf16x8*)(sx2 + b0x[j]);
        } else {
          int tap = s - 1, ky = tap / 3, kx = tap - ky * 3;
          int toff = (ky * 26 + kx) * 40 + hi4 * 8;
#pragma unroll
          for (int j = 0; j < 2; ++j) af[j] = *(const bf16x8*)(h0r + b0h[j] + toff);
        }
      };
      auto loadB0 = [&](int s, bf16x8* bc) {
#pragma unroll
        for (int g = 0; g < 4; ++g)
          bc[g] = *(const bf16x8*)(w0f + (s * 4 + g) * 512);
      };
      auto mfma0 = [&](bf16x8* af, bf16x8* bc) {
#pragma unroll
        for (int j = 0; j < 2; ++j)
#pragma unroll
          for (int g = 0; g < 4; ++g)
            a0[g][j] = __builtin_amdgcn_mfma_f32_16x16x32_bf16(af[j], bc[g], a0[g][j], 0, 0, 0);
      };

      bf16x8 afA[2], afB[2], bcA[4], bcB[4];
      loadA0(0, afA); loadB0(0, bcA);
      loadA0(1, afB); loadB0(1, bcB);
#pragma unroll 1
      for (int s = 0; s < 10; s += 2) {
        __builtin_amdgcn_s_setprio(1);
        mfma0(afA, bcA);
        __builtin_amdgcn_s_setprio(0);
        int s2 = (s + 2 < 10) ? s + 2 : 9;
        loadA0(s2, afA); loadB0(s2, bcA);
        __builtin_amdgcn_s_setprio(1);
        mfma0(afB, bcB);
        __builtin_amdgcn_s_setprio(0);
        int s3 = (s + 3 < 10) ? s + 3 : 9;
        loadA0(s3, afB); loadB0(s3, bcB);
      }

      // epilogue: lane owns (pix = (tb+j)*16 + hi4*4 + r, ch0)
#pragma unroll
      for (int j = 0; j < 2; ++j) {
        int p0 = (tb + j) * 16 + hi4 * 4;
        if (j < ntq && p0 < 168) {
          const __bf16* wpp = wcp0 + ch0 * 168 + p0;
          bf16x4 w_i = *(const bf16x4*)(wpp);
          bf16x4 w_f = *(const bf16x4*)(wpp + 5376);
          bf16x4 w_o = *(const bf16x4*)(wpp + 10752);
#pragma unroll
          for (int r = 0; r < 4; ++r) {
            int p = p0 + r;
            float c = c0r[j][r];
            float gi = a0[0][j][r];              // bias folded into k=18 tap
            float gf = a0[1][j][r];
            float gc = a0[2][j][r];
            float go = a0[3][j][r];
            float ig = sigm(gi + c * (float)w_i[r]);
            float fg = sigm(gf + c * (float)w_f[r]);
            float cn = fg * c + ig * ftanh(gc);
            float og = sigm(go + cn * (float)w_o[r]);
            float hn = og * ftanh(cn);
            c0r[j][r] = cn;
            int iy = p / 24, ix = p - iy * 24;
            h0w[((iy + 1) * 26 + ix + 1) * 40 + ch0] = (__bf16)hn;
          }
        }
      }
    }
    __syncthreads();   // the ONLY per-step barrier.
    // Hazard walk: h0w(t) writes vs L1 reads of h0w -> ordered here.
    // h1w(t-1) writes (prev L1) vs h1r(t) reads -> a wave reaches this
    // barrier only after finishing prev L1, so ordered too. Next-step L0
    // writes sh0[st&1]; concurrent L1(st) reads sh0[(st+1)&1]/sh1 only
    // -> disjoint. No end-of-step barrier needed.

    // ============ layer 1: 4 tiles/wave, single-A + dbuf-B ================
    {
      const int tb = m3 * 4;                       // tiles tb..tb+3 (11 dummy)
      const int ntp = (m3 == 2) ? 3 : 4;
      int b1h0[4], b1h1[4];
#pragma unroll
      for (int j = 0; j < 4; ++j) {
        int pr = (tb + j) * 16 + lo16;
        if (pr > 167) pr = 167;
        int iy = pr / 24, ix = pr - iy * 24;
        b1h0[j] = (iy * 26 + ix) * 40;
        b1h1[j] = (iy * 26 + ix) * 72;
      }
      f32x4 a1[4][4];
      {
        const float binit[4] = {bi1, bf1, bg1, bo1};   // bias folded into acc
#pragma unroll
        for (int g = 0; g < 4; ++g)
#pragma unroll
          for (int j = 0; j < 4; ++j)
            a1[g][j] = (f32x4){binit[g], binit[g], binit[g], binit[g]};
      }

      auto loadA1 = [&](int s, bf16x8* af) {
        if (s < 9) {
          int ky = s / 3, kx = s - ky * 3;
          int toff = (ky * 26 + kx) * 40 + hi4 * 8;
#pragma unroll
          for (int j = 0; j < 4; ++j) af[j] = *(const bf16x8*)(h0w + b1h0[j] + toff);
        } else {
          int t2 = s - 9, tap = t2 >> 1, hf = t2 & 1;
          int ky = tap / 3, kx = tap - ky * 3;
          int toff = (ky * 26 + kx) * 72 + hf * 32 + hi4 * 8;
#pragma unroll
          for (int j = 0; j < 4; ++j) af[j] = *(const bf16x8*)(h1r + b1h1[j] + toff);
        }
      };
      auto loadB1 = [&](int s, bf16x8* bc) {
#pragma unroll
        for (int g = 0; g < 4; ++g)
          bc[g] = *(const bf16x8*)(w1f + (s * 4 + g) * 512);
      };
      auto mfma1 = [&](bf16x8* af, bf16x8* bc) {
#pragma unroll
        for (int j = 0; j < 4; ++j) {
          if (j < ntp) {
#pragma unroll
            for (int g = 0; g < 4; ++g)
              a1[g][j] = __builtin_amdgcn_mfma_f32_16x16x32_bf16(af[j], bc[g], a1[g][j], 0, 0, 0);
          }
        }
      };

      bf16x8 af[4], bcA[4], bcB[4];
      loadA1(0, af); loadB1(0, bcA); loadB1(1, bcB);
#pragma unroll 1
      for (int s = 0; s < 26; s += 2) {
        __builtin_amdgcn_s_setprio(1);
        mfma1(af, bcA);                            // (af@s, bcA@s)
        __builtin_amdgcn_s_setprio(0);
        loadB1((s + 2 < 27) ? s + 2 : 26, bcA);
        loadA1(s + 1, af);
        __builtin_amdgcn_s_setprio(1);
        mfma1(af, bcB);                            // (af@s+1, bcB@s+1)
        __builtin_amdgcn_s_setprio(0);
        loadB1((s + 3 < 27) ? s + 3 : 26, bcB);
        loadA1((s + 2 < 27) ? s + 2 : 26, af);
      }
      __builtin_amdgcn_s_setprio(1);
      mfma1(af, bcA);                              // s = 26 tail
      __builtin_amdgcn_s_setprio(0);

      // epilogue: lane owns (pix = (tb+j)*16 + hi4*4 + r, ch1); direct write
#pragma unroll
      for (int j = 0; j < 4; ++j) {
        int p0 = (tb + j) * 16 + hi4 * 4;
        if (j < ntp && p0 < 168) {
          const __bf16* wpp = wcp1 + ch1 * 168 + p0;
          bf16x4 w_i = *(const bf16x4*)(wpp);
          bf16x4 w_f = *(const bf16x4*)(wpp + 10752);
          bf16x4 w_o = *(const bf16x4*)(wpp + 21504);
#pragma unroll
          for (int r = 0; r < 4; ++r) {
            int p = p0 + r;
            float c = c1r[j][r];
            float gi = a1[0][j][r];
            float gf = a1[1][j][r];
            float gc = a1[2][j][r];
            float go = a1[3][j][r];
            float ig = sigm(gi + c * (float)w_i[r]);
            float fg = sigm(gf + c * (float)w_f[r]);
            float cn = fg * c + ig * ftanh(gc);
            float og = sigm(go + cn * (float)w_o[r]);
            float hn = og * ftanh(cn);
            c1r[j][r] = cn;
            int iy = p / 24, ix = p - iy * 24;
            h1w[((iy + 1) * 26 + ix + 1) * 72 + ch1] = (__bf16)hn;
          }
        }
      }
    }
  }
  __syncthreads();     // h1(7) (in sh1 buffer 1) visible before FC reads

  // ================= FC heads (h1 final in sh1 buffer (6+1)&1 = 1) ========
  {
    const __bf16* h1f = sh1 + SH1N;
    const int o = t & 3, pg = t >> 2;    // o: 16 n's (o*16..); pg 0..191
    float part[16];
#pragma unroll
    for (int q = 0; q < 16; ++q) part[q] = 0.f;
    if (pg < 168) {
      int iy = pg / 24, ix = pg - iy * 24;
      const __bf16* hrow = h1f + ((iy + 1) * 26 + ix + 1) * 72;
      const __bf16* wrow = wfc2 + (size_t)pg * 4096 + o * 16;
#pragma unroll 1
      for (int c8 = 0; c8 < 8; ++c8) {
        bf16x8 hv = *(const bf16x8*)(hrow + c8 * 8);
#pragma unroll
        for (int u = 0; u < 8; ++u) {
          float hvf = (float)hv[u];
          const __bf16* wp = wrow + (c8 * 8 + u) * 64;
          bf16x8 wv0 = ntld8(wp);        // non-temporal: don't evict wp1/wp0
          bf16x8 wv1 = ntld8(wp + 8);
#pragma unroll
          for (int q = 0; q < 8; ++q) {
            part[q] += hvf * (float)wv0[q];
            part[8 + q] += hvf * (float)wv1[q];
          }
        }
      }
    }
    // wave-level reduce: lanes sharing o (lane bits 2..5) sum together
#pragma unroll
    for (int q = 0; q < 16; ++q) {
      float v = part[q];
      v += __shfl_xor(v, 4);
      v += __shfl_xor(v, 8);
      v += __shfl_xor(v, 16);
      v += __shfl_xor(v, 32);
      part[q] = v;
    }
    float* sacc = (float*)sx2;   // sx2 dead; 12 waves * 64 f32 = 3 KB
    if (L < 4) {
#pragma unroll
      for (int q = 0; q < 16; ++q) sacc[w * 64 + L * 16 + q] = part[q];
    }
    __syncthreads();
    if (t < 64) {
      float s = fc1b[t];
#pragma unroll
      for (int w2 = 0; w2 < 12; ++w2) s += sacc[w2 * 64 + t];
      out[(size_t)b * 128 + t] = fmaxf(s, 0.f);
    } else if (t < 128) {
      int j = t - 64;
      float s = exb[j];
      for (int k = 0; k < 24; ++k) s += x_ex[b * 24 + k] * exw[j * 24 + k];
      out[(size_t)b * 128 + 64 + j] = fmaxf(s, 0.f);
    }
  }
}

// ---------------- launcher ----------------
extern "C" void kernel_launch(void* const* d_in, const int* in_sizes, int n_in,
                              void* d_out, int out_size, void* d_ws, size_t ws_size,
                              hipStream_t stream) {
  const float* input = (const float*)d_in[0];
  const float* x_ex  = (const float*)d_in[1];
  const float* Wx0   = (const float*)d_in[2];
  const float* bx0   = (const float*)d_in[3];
  const float* Wh0   = (const float*)d_in[4];
  const float* Wc0   = (const float*)d_in[5];
  const float* Wx1   = (const float*)d_in[6];
  const float* bx1   = (const float*)d_in[7];
  const float* Wh1   = (const float*)d_in[8];
  const float* Wc1   = (const float*)d_in[9];
  const float* fc1w  = (const float*)d_in[10];
  const float* fc1b  = (const float*)d_in[11];
  const float* exw   = (const float*)d_in[12];
  const float* exb   = (const float*)d_in[13];
  (void)in_sizes; (void)n_in;

  if (ws_size < WS_NEED) {
    hipMemsetAsync(d_out, 0, (size_t)out_size * 4, stream);
    return;
  }

  char* ws = (char*)d_ws;
  __bf16* wp0  = (__bf16*)(ws + OFF_WP0);
  __bf16* wp1  = (__bf16*)(ws + OFF_WP1);
  __bf16* wfc2 = (__bf16*)(ws + OFF_WFC);
  __bf16* wcp0 = (__bf16*)(ws + OFF_WCP0);
  __bf16* wcp1 = (__bf16*)(ws + OFF_WCP1);

  pack_w0<<<160, 256, 0, stream>>>(Wx0, Wh0, bx0, wp0);
  pack_w1<<<864, 256, 0, stream>>>(Wx1, Wh1, wp1);
  pack_wfc<<<2688, 256, 0, stream>>>(fc1w, wfc2);
  pack_wc<<<189, 256, 0, stream>>>(Wc0, Wc1, wcp0, wcp1);

  convlstm_persistent<<<2048, 768, 0, stream>>>(
      input, x_ex, wp0, wp1, wfc2, bx1, wcp0, wcp1, fc1b, exw, exb,
      (float*)d_out);
}